// Round 10
// baseline (158.112 us; speedup 1.0000x reference)
//
#include <hip/hip_runtime.h>
#include <hip/hip_bf16.h>

#define HIDDEN 4096
#define INTER 11008
#define MTOK 128  // 4*32 tokens

typedef float f32x4 __attribute__((ext_vector_type(4)));
typedef short s16x8 __attribute__((ext_vector_type(8)));

__device__ __forceinline__ unsigned short f2bf(float f) {
    unsigned int u = __float_as_uint(f);
    u += 0x7FFFu + ((u >> 16) & 1u);
    return (unsigned short)(u >> 16);
}

__device__ __forceinline__ s16x8 cvt8(f32x4 a, f32x4 b) {
    s16x8 r;
    r[0] = (short)f2bf(a[0]); r[1] = (short)f2bf(a[1]);
    r[2] = (short)f2bf(a[2]); r[3] = (short)f2bf(a[3]);
    r[4] = (short)f2bf(b[0]); r[5] = (short)f2bf(b[1]);
    r[6] = (short)f2bf(b[2]); r[7] = (short)f2bf(b[3]);
    return r;
}

// ---------- kernel 1: x fp32 -> bf16 in MFMA FRAGMENT ORDER ----------
// Group g = ((s64*8 + mt)*2 + kk2)*64 + lane holds 8 bf16 of
//   x[mt*16 + (lane&15)][s64*64 + kk2*32 + (lane>>4)*8 + e]
__global__ __launch_bounds__(256) void k_convert_x2(const float* __restrict__ x,
                                                    s16x8* __restrict__ xf) {
    int t = blockIdx.x * 256 + threadIdx.x;  // [0, 65536)
    int lane = t & 63, kk2 = (t >> 6) & 1, mt = (t >> 7) & 7, s64 = t >> 10;
    int row = mt * 16 + (lane & 15);
    int k0 = s64 * 64 + kk2 * 32 + (lane >> 4) * 8;
    const float* p = x + (size_t)row * HIDDEN + k0;
    f32x4 a = *reinterpret_cast<const f32x4*>(p);
    f32x4 b = *reinterpret_cast<const f32x4*>(p + 4);
    xf[t] = cvt8(a, b);
}

// ---------- GEMM building blocks, K_STEP = 256 ----------
// A: 16 frags (2 mt x 8 kk) from frag-ordered buffer; all 1KB-coalesced loads.
__device__ __forceinline__ void loadA8(const s16x8* __restrict__ afb, int mt0, int s,
                                       int lane, s16x8 a[16]) {
#pragma unroll
    for (int kk = 0; kk < 8; ++kk)
#pragma unroll
        for (int mi = 0; mi < 2; ++mi) {
            int s64 = s * 4 + (kk >> 1), kk2 = kk & 1;
            a[kk * 2 + mi] = afb[(size_t)(((s64 * 8 + mt0 + mi) * 2 + kk2) * 64 + lane)];
        }
}

// W: 16 rows x 1KB fp32; ONE full-wave dwordx4 instr per row (1KB contiguous/visit).
template <int LDK>
__device__ __forceinline__ void loadW16(const float* __restrict__ w, int row0,
                                        int lane, int s, f32x4 r[16]) {
    const float* base = w + (size_t)row0 * LDK + s * 256 + lane * 4;
#pragma unroll
    for (int j = 0; j < 16; ++j)
        r[j] = *reinterpret_cast<const f32x4*>(base + (size_t)j * LDK);
}

// cvt fp32->bf16, write to LDS rows of 512B with XOR(row&7)<<4 swizzle.
__device__ __forceinline__ void writeW16(char* wb, int wv, int lane, const f32x4 r[16]) {
#pragma unroll
    for (int j = 0; j < 16; ++j) {
        int row = wv * 16 + j;
        ushort4 o;
        o.x = f2bf(r[j][0]); o.y = f2bf(r[j][1]);
        o.z = f2bf(r[j][2]); o.w = f2bf(r[j][3]);
        *reinterpret_cast<ushort4*>(wb + row * 512 + ((lane * 8) ^ ((row & 7) << 4))) = o;
    }
}

// compute: wave = 2 mt x 64 cols x K=256 -> 64 MFMA, 32 swizzled b128 LDS reads.
__device__ __forceinline__ void comp8(const char* wb, int lane, const s16x8 a[16],
                                      f32x4 acc[2][4]) {
    const int r16 = lane & 15, g4 = lane >> 4;
#pragma unroll
    for (int nf = 0; nf < 4; ++nf) {
        int row = nf * 16 + r16;
        const char* wrp = wb + row * 512;
        unsigned swz = (unsigned)((row & 7) << 4);
#pragma unroll
        for (int kk = 0; kk < 8; ++kk) {
            s16x8 bf = *reinterpret_cast<const s16x8*>(wrp + ((unsigned)(kk * 64 + g4 * 16) ^ swz));
#pragma unroll
            for (int mi = 0; mi < 2; ++mi)
                acc[mi][nf] = __builtin_amdgcn_mfma_f32_16x16x32_bf16(a[kk * 2 + mi], bf,
                                                                      acc[mi][nf], 0, 0, 0);
        }
    }
}

// K-loop with per-block k-phase rotation: block processes steps in the order
// sbeg+phase, sbeg+phase+1, ..., wrapping mod nsteps. Decorrelates the chip-wide
// k-position so all HBM channels are active concurrently.
template <int LDK>
__device__ __forceinline__ void gemm9(const s16x8* __restrict__ afb,
                                      const float* __restrict__ w, int n0,
                                      int sbeg, int nsteps, int phase,
                                      f32x4 acc[2][4], char* wb) {
    const int tid = threadIdx.x, wv = tid >> 6, lane = tid & 63;
    const int mt0 = wv * 2;
    s16x8 a[16];
    f32x4 rw[16];

    loadW16<LDK>(w, n0 + wv * 16, lane, sbeg + phase, rw);
    writeW16(wb, wv, lane, rw);
    __syncthreads();

    for (int t = 0; t < nsteps; ++t) {
        const int buf = t & 1;
        int tc = t + phase;     if (tc >= nsteps) tc -= nsteps;
        int tn = t + 1 + phase; if (tn >= nsteps) tn -= nsteps;
        const int scur = sbeg + tc, snext = sbeg + tn;
        loadA8(afb, mt0, scur, lane, a);                    // A(t) issued FIRST
        __builtin_amdgcn_sched_barrier(0);
        if (t + 1 < nsteps) loadW16<LDK>(w, n0 + wv * 16, lane, snext, rw);
        __builtin_amdgcn_sched_barrier(0);
        comp8(wb + buf * 32768, lane, a, acc);              // waits A; W stays in flight
        __builtin_amdgcn_sched_barrier(0);
        if (t + 1 < nsteps) writeW16(wb + (buf ^ 1) * 32768, wv, lane, rw);
        __syncthreads();
    }
}

// ---------- kernel 2: gate & up GEMM ----------
// grid.x = 172 * 2 * Sg ; block = 256 (4 waves); N_tile = 64 weight rows.
__global__ __launch_bounds__(256, 2) void k_gateup9(const s16x8* __restrict__ xf,
                                                    const float* __restrict__ wg,
                                                    const float* __restrict__ wu,
                                                    float* __restrict__ pg,
                                                    float* __restrict__ pu, int Sg) {
    __shared__ __align__(16) char wb[2 * 32768];  // 64 KB
    const int gid = blockIdx.x;
    const int nt = gid % 172, rest = gid / 172;
    const int mat = rest & 1, kc = rest >> 1;
    const int n0 = nt * 64;
    const int nsteps = 16 / Sg;                   // K-steps of 256; total 16
    const int sbeg = kc * nsteps;
    const int phase = gid % nsteps;

    f32x4 acc[2][4] = {};
    gemm9<HIDDEN>(xf, mat ? wu : wg, n0, sbeg, nsteps, phase, acc, wb);

    const int lane = threadIdx.x & 63, wv = threadIdx.x >> 6;
    const int r16 = lane & 15, g4 = lane >> 4;
    float* p = (mat ? pu : pg) + (size_t)kc * (MTOK * INTER);
#pragma unroll
    for (int mi = 0; mi < 2; ++mi)
#pragma unroll
        for (int nf = 0; nf < 4; ++nf)
#pragma unroll
            for (int r = 0; r < 4; ++r) {
                int m = (wv * 2 + mi) * 16 + g4 * 4 + r;
                p[(size_t)m * INTER + n0 + nf * 16 + r16] = acc[mi][nf][r];
            }
}

// ---------- kernel 3: combine + silu*up -> h in FRAG ORDER (bf16) ----------
__global__ __launch_bounds__(256) void k_combine2(const float* __restrict__ pg,
                                                  const float* __restrict__ pu,
                                                  s16x8* __restrict__ hf, int Sg) {
    int t = blockIdx.x * 256 + threadIdx.x;  // [0, 176128)
    int lane = t & 63, r16 = lane & 15, g4 = (lane >> 4) & 3;
    int kk2 = (t >> 6) & 1, mt = (t >> 7) & 7, s64 = t >> 10;
    int m = mt * 16 + r16;
    size_t base = (size_t)m * INTER + s64 * 64 + kk2 * 32 + g4 * 8;

    f32x4 g0 = (f32x4)0.0f, g1 = (f32x4)0.0f, u0 = (f32x4)0.0f, u1 = (f32x4)0.0f;
    for (int c = 0; c < Sg; ++c) {
        const float* pgc = pg + (size_t)c * (MTOK * INTER) + base;
        const float* puc = pu + (size_t)c * (MTOK * INTER) + base;
        g0 += *reinterpret_cast<const f32x4*>(pgc);
        g1 += *reinterpret_cast<const f32x4*>(pgc + 4);
        u0 += *reinterpret_cast<const f32x4*>(puc);
        u1 += *reinterpret_cast<const f32x4*>(puc + 4);
    }
    f32x4 h0, h1;
#pragma unroll
    for (int e = 0; e < 4; ++e) {
        h0[e] = g0[e] / (1.0f + __expf(-g0[e])) * u0[e];
        h1[e] = g1[e] / (1.0f + __expf(-g1[e])) * u1[e];
    }
    hf[t] = cvt8(h0, h1);
}

// ---------- kernel 4: down GEMM ----------
// grid.x = 64 * Sd ; block = 256. K-steps [0,43) of 256 split across Sd chunks.
__global__ __launch_bounds__(256, 2) void k_down9(const s16x8* __restrict__ hf,
                                                  const float* __restrict__ wd,
                                                  float* __restrict__ pd, int Sd) {
    __shared__ __align__(16) char wb[2 * 32768];
    const int gid = blockIdx.x;
    const int nt = gid % 64, kc = gid / 64;
    const int n0 = nt * 64;
    const int sbeg = (43 * kc) / Sd, send = (43 * (kc + 1)) / Sd;
    const int nsteps = send - sbeg;
    const int phase = gid % nsteps;

    f32x4 acc[2][4] = {};
    gemm9<INTER>(hf, wd, n0, sbeg, nsteps, phase, acc, wb);

    const int lane = threadIdx.x & 63, wv = threadIdx.x >> 6;
    const int r16 = lane & 15, g4 = lane >> 4;
    float* p = pd + (size_t)kc * (MTOK * HIDDEN);
#pragma unroll
    for (int mi = 0; mi < 2; ++mi)
#pragma unroll
        for (int nf = 0; nf < 4; ++nf)
#pragma unroll
            for (int r = 0; r < 4; ++r) {
                int m = (wv * 2 + mi) * 16 + g4 * 4 + r;
                p[(size_t)m * HIDDEN + n0 + nf * 16 + r16] = acc[mi][nf][r];
            }
}

// ---------- kernel 5: reduce Sd partials -> out ----------
__global__ __launch_bounds__(256) void k_reduce(const float* __restrict__ pd,
                                                float* __restrict__ out, int Sd) {
    int i = (blockIdx.x * 256 + threadIdx.x) * 4;
    const int NT = MTOK * HIDDEN;
    f32x4 s = (f32x4)0.0f;
    for (int c = 0; c < Sd; ++c)
        s += *reinterpret_cast<const f32x4*>(pd + (size_t)c * NT + i);
    *reinterpret_cast<f32x4*>(out + i) = s;
}

extern "C" void kernel_launch(void* const* d_in, const int* in_sizes, int n_in,
                              void* d_out, int out_size, void* d_ws, size_t ws_size,
                              hipStream_t stream) {
    const float* x  = (const float*)d_in[0];
    const float* wg = (const float*)d_in[1];
    const float* wu = (const float*)d_in[2];
    const float* wd = (const float*)d_in[3];
    float* out = (float*)d_out;

    const size_t XB = 1048576;                      // xf frag-ordered bf16
    const size_t HB = 2818048;                      // hf frag-ordered bf16
    const size_t PGU = (size_t)MTOK * INTER * 4;    // per split per matrix
    const size_t PD  = (size_t)MTOK * HIDDEN * 4;   // per split
    const int cfg[4][2] = {{2, 8}, {1, 4}, {1, 2}, {1, 1}};
    int Sg = 1, Sd = 1;
    for (int c = 0; c < 4; ++c) {
        size_t need = XB + HB + 2 * (size_t)cfg[c][0] * PGU + (size_t)cfg[c][1] * PD;
        if (need <= ws_size) { Sg = cfg[c][0]; Sd = cfg[c][1]; break; }
    }

    char* ws = (char*)d_ws;
    s16x8* xf = (s16x8*)ws;
    s16x8* hf = (s16x8*)(ws + XB);
    float* pg = (float*)(ws + XB + HB);
    float* pu = pg + (size_t)Sg * (MTOK * INTER);
    float* pd = pu + (size_t)Sg * (MTOK * INTER);

    k_convert_x2<<<256, 256, 0, stream>>>(x, xf);
    k_gateup9<<<172 * 2 * Sg, 256, 0, stream>>>(xf, wg, wu, pg, pu, Sg);
    k_combine2<<<688, 256, 0, stream>>>(pg, pu, hf, Sg);
    k_down9<<<64 * Sd, 256, 0, stream>>>(hf, wd, pd, Sd);
    k_reduce<<<512, 256, 0, stream>>>(pd, out, Sd);
}

// Round 11
// 155.055 us; speedup vs baseline: 1.0197x; 1.0197x over previous
//
#include <hip/hip_runtime.h>
#include <hip/hip_bf16.h>

#define HIDDEN 4096
#define INTER 11008
#define MTOK 128  // 4*32 tokens

typedef float f32x4 __attribute__((ext_vector_type(4)));
typedef short s16x8 __attribute__((ext_vector_type(8)));

__device__ __forceinline__ unsigned short f2bf(float f) {
    unsigned int u = __float_as_uint(f);
    u += 0x7FFFu + ((u >> 16) & 1u);
    return (unsigned short)(u >> 16);
}

__device__ __forceinline__ s16x8 cvt8(f32x4 a, f32x4 b) {
    s16x8 r;
    r[0] = (short)f2bf(a[0]); r[1] = (short)f2bf(a[1]);
    r[2] = (short)f2bf(a[2]); r[3] = (short)f2bf(a[3]);
    r[4] = (short)f2bf(b[0]); r[5] = (short)f2bf(b[1]);
    r[6] = (short)f2bf(b[2]); r[7] = (short)f2bf(b[3]);
    return r;
}

// ---------- kernel 1: x fp32 -> bf16 in MFMA FRAGMENT ORDER ----------
// Group g = ((s64*8 + mt)*2 + kk2)*64 + lane holds 8 bf16 of
//   x[mt*16 + (lane&15)][s64*64 + kk2*32 + (lane>>4)*8 + e]
__global__ __launch_bounds__(256) void k_convert_x2(const float* __restrict__ x,
                                                    s16x8* __restrict__ xf) {
    int t = blockIdx.x * 256 + threadIdx.x;  // [0, 65536)
    int lane = t & 63, kk2 = (t >> 6) & 1, mt = (t >> 7) & 7, s64 = t >> 10;
    int row = mt * 16 + (lane & 15);
    int k0 = s64 * 64 + kk2 * 32 + (lane >> 4) * 8;
    const float* p = x + (size_t)row * HIDDEN + k0;
    f32x4 a = *reinterpret_cast<const f32x4*>(p);
    f32x4 b = *reinterpret_cast<const f32x4*>(p + 4);
    xf[t] = cvt8(a, b);
}

// ---------- GEMM building blocks, K_STEP = 256 ----------
// A: 16 frags (2 mt x 8 kk) from frag-ordered buffer; all 1KB-coalesced loads.
__device__ __forceinline__ void loadA8(const s16x8* __restrict__ afb, int mt0, int s,
                                       int lane, s16x8 a[16]) {
#pragma unroll
    for (int kk = 0; kk < 8; ++kk)
#pragma unroll
        for (int mi = 0; mi < 2; ++mi) {
            int s64 = s * 4 + (kk >> 1), kk2 = kk & 1;
            a[kk * 2 + mi] = afb[(size_t)(((s64 * 8 + mt0 + mi) * 2 + kk2) * 64 + lane)];
        }
}

// W: 16 rows x 1KB fp32; ONE full-wave dwordx4 instr per row (1KB contiguous/visit).
template <int LDK>
__device__ __forceinline__ void loadW16(const float* __restrict__ w, int row0,
                                        int lane, int s, f32x4 r[16]) {
    const float* base = w + (size_t)row0 * LDK + s * 256 + lane * 4;
#pragma unroll
    for (int j = 0; j < 16; ++j)
        r[j] = *reinterpret_cast<const f32x4*>(base + (size_t)j * LDK);
}

// cvt fp32->bf16, write to LDS rows of 512B with XOR(row&7)<<4 swizzle.
__device__ __forceinline__ void writeW16(char* wb, int wv, int lane, const f32x4 r[16]) {
#pragma unroll
    for (int j = 0; j < 16; ++j) {
        int row = wv * 16 + j;
        ushort4 o;
        o.x = f2bf(r[j][0]); o.y = f2bf(r[j][1]);
        o.z = f2bf(r[j][2]); o.w = f2bf(r[j][3]);
        *reinterpret_cast<ushort4*>(wb + row * 512 + ((lane * 8) ^ ((row & 7) << 4))) = o;
    }
}

// compute: wave = 2 mt x 64 cols x K=256 -> 64 MFMA, 32 swizzled b128 LDS reads.
__device__ __forceinline__ void comp8(const char* wb, int lane, const s16x8 a[16],
                                      f32x4 acc[2][4]) {
    const int r16 = lane & 15, g4 = lane >> 4;
#pragma unroll
    for (int nf = 0; nf < 4; ++nf) {
        int row = nf * 16 + r16;
        const char* wrp = wb + row * 512;
        unsigned swz = (unsigned)((row & 7) << 4);
#pragma unroll
        for (int kk = 0; kk < 8; ++kk) {
            s16x8 bf = *reinterpret_cast<const s16x8*>(wrp + ((unsigned)(kk * 64 + g4 * 16) ^ swz));
#pragma unroll
            for (int mi = 0; mi < 2; ++mi)
                acc[mi][nf] = __builtin_amdgcn_mfma_f32_16x16x32_bf16(a[kk * 2 + mi], bf,
                                                                      acc[mi][nf], 0, 0, 0);
        }
    }
}

// K-loop with per-block k-phase rotation: block processes steps in the order
// sbeg+phase, sbeg+phase+1, ..., wrapping mod nsteps. Decorrelates the chip-wide
// k-position so all HBM channels are active concurrently.
template <int LDK>
__device__ __forceinline__ void gemm9(const s16x8* __restrict__ afb,
                                      const float* __restrict__ w, int n0,
                                      int sbeg, int nsteps, int phase,
                                      f32x4 acc[2][4], char* wb) {
    const int tid = threadIdx.x, wv = tid >> 6, lane = tid & 63;
    const int mt0 = wv * 2;
    s16x8 a[16];
    f32x4 rw[16];

    loadW16<LDK>(w, n0 + wv * 16, lane, sbeg + phase, rw);
    writeW16(wb, wv, lane, rw);
    __syncthreads();

    for (int t = 0; t < nsteps; ++t) {
        const int buf = t & 1;
        int tc = t + phase;     if (tc >= nsteps) tc -= nsteps;
        int tn = t + 1 + phase; if (tn >= nsteps) tn -= nsteps;
        const int scur = sbeg + tc, snext = sbeg + tn;
        loadA8(afb, mt0, scur, lane, a);                    // A(t) issued FIRST
        __builtin_amdgcn_sched_barrier(0);
        if (t + 1 < nsteps) loadW16<LDK>(w, n0 + wv * 16, lane, snext, rw);
        __builtin_amdgcn_sched_barrier(0);
        comp8(wb + buf * 32768, lane, a, acc);              // waits A; W stays in flight
        __builtin_amdgcn_sched_barrier(0);
        if (t + 1 < nsteps) writeW16(wb + (buf ^ 1) * 32768, wv, lane, rw);
        __syncthreads();
    }
}

// ---------- kernel 2: gate & up GEMM ----------
// grid.x = 172 * 2 * Sg ; block = 256 (4 waves); N_tile = 64 weight rows.
__global__ __launch_bounds__(256, 2) void k_gateup9(const s16x8* __restrict__ xf,
                                                    const float* __restrict__ wg,
                                                    const float* __restrict__ wu,
                                                    float* __restrict__ pg,
                                                    float* __restrict__ pu, int Sg) {
    __shared__ __align__(16) char wb[2 * 32768];  // 64 KB
    const int gid = blockIdx.x;
    const int nt = gid % 172, rest = gid / 172;
    const int mat = rest & 1, kc = rest >> 1;
    const int n0 = nt * 64;
    const int nsteps = 16 / Sg;                   // K-steps of 256; total 16
    const int sbeg = kc * nsteps;
    const int phase = gid % nsteps;

    f32x4 acc[2][4] = {};
    gemm9<HIDDEN>(xf, mat ? wu : wg, n0, sbeg, nsteps, phase, acc, wb);

    const int lane = threadIdx.x & 63, wv = threadIdx.x >> 6;
    const int r16 = lane & 15, g4 = lane >> 4;
    float* p = (mat ? pu : pg) + (size_t)kc * (MTOK * INTER);
#pragma unroll
    for (int mi = 0; mi < 2; ++mi)
#pragma unroll
        for (int nf = 0; nf < 4; ++nf)
#pragma unroll
            for (int r = 0; r < 4; ++r) {
                int m = (wv * 2 + mi) * 16 + g4 * 4 + r;
                p[(size_t)m * INTER + n0 + nf * 16 + r16] = acc[mi][nf][r];
            }
}

// ---------- kernel 3: combine + silu*up -> h in FRAG ORDER (bf16) ----------
__global__ __launch_bounds__(256) void k_combine2(const float* __restrict__ pg,
                                                  const float* __restrict__ pu,
                                                  s16x8* __restrict__ hf, int Sg) {
    int t = blockIdx.x * 256 + threadIdx.x;  // [0, 176128)
    int lane = t & 63, r16 = lane & 15, g4 = (lane >> 4) & 3;
    int kk2 = (t >> 6) & 1, mt = (t >> 7) & 7, s64 = t >> 10;
    int m = mt * 16 + r16;
    size_t base = (size_t)m * INTER + s64 * 64 + kk2 * 32 + g4 * 8;

    f32x4 g0 = (f32x4)0.0f, g1 = (f32x4)0.0f, u0 = (f32x4)0.0f, u1 = (f32x4)0.0f;
    for (int c = 0; c < Sg; ++c) {
        const float* pgc = pg + (size_t)c * (MTOK * INTER) + base;
        const float* puc = pu + (size_t)c * (MTOK * INTER) + base;
        g0 += *reinterpret_cast<const f32x4*>(pgc);
        g1 += *reinterpret_cast<const f32x4*>(pgc + 4);
        u0 += *reinterpret_cast<const f32x4*>(puc);
        u1 += *reinterpret_cast<const f32x4*>(puc + 4);
    }
    f32x4 h0, h1;
#pragma unroll
    for (int e = 0; e < 4; ++e) {
        h0[e] = g0[e] / (1.0f + __expf(-g0[e])) * u0[e];
        h1[e] = g1[e] / (1.0f + __expf(-g1[e])) * u1[e];
    }
    hf[t] = cvt8(h0, h1);
}

// ---------- kernel 4: down GEMM ----------
// grid.x = 64 * Sd ; block = 256. K-steps [0,43) of 256 split across Sd chunks.
__global__ __launch_bounds__(256, 2) void k_down9(const s16x8* __restrict__ hf,
                                                  const float* __restrict__ wd,
                                                  float* __restrict__ pd, int Sd) {
    __shared__ __align__(16) char wb[2 * 32768];
    const int gid = blockIdx.x;
    const int nt = gid % 64, kc = gid / 64;
    const int n0 = nt * 64;
    const int sbeg = (43 * kc) / Sd, send = (43 * (kc + 1)) / Sd;
    const int nsteps = send - sbeg;
    const int phase = gid % nsteps;

    f32x4 acc[2][4] = {};
    gemm9<INTER>(hf, wd, n0, sbeg, nsteps, phase, acc, wb);

    const int lane = threadIdx.x & 63, wv = threadIdx.x >> 6;
    const int r16 = lane & 15, g4 = lane >> 4;
    float* p = pd + (size_t)kc * (MTOK * HIDDEN);
#pragma unroll
    for (int mi = 0; mi < 2; ++mi)
#pragma unroll
        for (int nf = 0; nf < 4; ++nf)
#pragma unroll
            for (int r = 0; r < 4; ++r) {
                int m = (wv * 2 + mi) * 16 + g4 * 4 + r;
                p[(size_t)m * HIDDEN + n0 + nf * 16 + r16] = acc[mi][nf][r];
            }
}

// ---------- kernel 5: reduce Sd partials -> out ----------
__global__ __launch_bounds__(256) void k_reduce(const float* __restrict__ pd,
                                                float* __restrict__ out, int Sd) {
    int i = (blockIdx.x * 256 + threadIdx.x) * 4;
    const int NT = MTOK * HIDDEN;
    f32x4 s = (f32x4)0.0f;
    for (int c = 0; c < Sd; ++c)
        s += *reinterpret_cast<const f32x4*>(pd + (size_t)c * NT + i);
    *reinterpret_cast<f32x4*>(out + i) = s;
}

extern "C" void kernel_launch(void* const* d_in, const int* in_sizes, int n_in,
                              void* d_out, int out_size, void* d_ws, size_t ws_size,
                              hipStream_t stream) {
    const float* x  = (const float*)d_in[0];
    const float* wg = (const float*)d_in[1];
    const float* wu = (const float*)d_in[2];
    const float* wd = (const float*)d_in[3];
    float* out = (float*)d_out;

    const size_t XB = 1048576;                      // xf frag-ordered bf16
    const size_t HB = 2818048;                      // hf frag-ordered bf16
    const size_t PGU = (size_t)MTOK * INTER * 4;    // per split per matrix
    const size_t PD  = (size_t)MTOK * HIDDEN * 4;   // per split
    const int cfg[4][2] = {{2, 8}, {1, 4}, {1, 2}, {1, 1}};
    int Sg = 1, Sd = 1;
    for (int c = 0; c < 4; ++c) {
        size_t need = XB + HB + 2 * (size_t)cfg[c][0] * PGU + (size_t)cfg[c][1] * PD;
        if (need <= ws_size) { Sg = cfg[c][0]; Sd = cfg[c][1]; break; }
    }

    char* ws = (char*)d_ws;
    s16x8* xf = (s16x8*)ws;
    s16x8* hf = (s16x8*)(ws + XB);
    float* pg = (float*)(ws + XB + HB);
    float* pu = pg + (size_t)Sg * (MTOK * INTER);
    float* pd = pu + (size_t)Sg * (MTOK * INTER);

    k_convert_x2<<<256, 256, 0, stream>>>(x, xf);
    k_gateup9<<<172 * 2 * Sg, 256, 0, stream>>>(xf, wg, wu, pg, pu, Sg);
    k_combine2<<<688, 256, 0, stream>>>(pg, pu, hf, Sg);
    k_down9<<<64 * Sd, 256, 0, stream>>>(hf, wd, pd, Sd);
    k_reduce<<<512, 256, 0, stream>>>(pd, out, Sd);
}